// Round 8
// baseline (574.063 us; speedup 1.0000x reference)
//
#include <hip/hip_runtime.h>

// MeanShift++ dense-grid, distinct-bin formulation, v6.
// Identity 1: ref pipeline == 5-tap triangular conv [1,2,3,2,1]^3 over per-bin
// sums/counts. Identity 2: result depends only on bin => per-step work is per
// OCCUPIED BIN (shrinking); per-point state via 1-tap lookups.
// v6 (vs v5): conv parallelized 8 lanes/item (16 taps/lane, shfl_xor reduce).
// r7 counters showed k_fused at 8% occupancy / 2% VALU: only ~940 waves held
// conv work and VGPR-limited load batching serialized the 125 taps.

constexpr float BW   = 0.1f;
constexpr float TOL2 = 1e-6f;            // (1e-3)^2
constexpr int DIM  = 112, OFF = 56;      // bins in [-56,55]; |x|<5.6 covered
constexpr int DIM2 = DIM * DIM;
constexpr int CELLS = DIM * DIM * DIM;   // 1,404,928
constexpr int CLW = CELLS / 32;
constexpr int RDIM = 16, RC = 7;         // 16^3 regions of 7^3 cells
constexpr int NREG = RDIM * RDIM * RDIM; // 4096
constexpr int RC3 = RC * RC * RC;        // 343
constexpr int NB_A = 128, BLK = 256;
constexpr float FPS = 16777216.0f;       // 2^24 fixed-point scale
constexpr double FPSI = 1.0 / 16777216.0;

typedef float vf2 __attribute__((ext_vector_type(2)));

__device__ __forceinline__ int clampb(int v) { return v < 0 ? 0 : (v > DIM - 1 ? DIM - 1 : v); }
__device__ __forceinline__ int binf(float v) { return clampb((int)(v / BW) + OFF); }  // IEEE div+trunc == ref
__device__ __forceinline__ int flatb(int bx, int by, int bz) { return (bx * DIM + by) * DIM + bz; }
__device__ __forceinline__ int regOf(int bx, int by, int bz) {
    return ((bx / RC) * RDIM + (by / RC)) * RDIM + (bz / RC);
}
__device__ __forceinline__ int lcOf(int bx, int by, int bz) {
    return ((bx % RC) * RC + (by % RC)) * RC + (bz % RC);
}

__device__ __forceinline__ void pk_add(float* p, float a, float b) {
#if defined(__has_builtin) && __has_builtin(__builtin_amdgcn_global_atomic_fadd_v2f32)
    vf2 v = {a, b};
    __builtin_amdgcn_global_atomic_fadd_v2f32((vf2*)p, v);
#else
    atomicAdd(p, a);
    atomicAdd(p + 1, b);
#endif
}

// ---- pass A1: per-block region histogram (LDS) + streaming zero of grid B ----
__launch_bounds__(BLK)
__global__ void k_histA(const float* __restrict__ X, int n, int* __restrict__ blockHist,
                        float4* __restrict__ zeroB) {
    __shared__ int h[NREG];
    for (int i = threadIdx.x; i < NREG; i += blockDim.x) h[i] = 0;
    __syncthreads();
    int stride = gridDim.x * blockDim.x;
    for (int i = blockIdx.x * blockDim.x + threadIdx.x; i < n; i += stride) {
        float x = X[3 * i + 0], y = X[3 * i + 1], z = X[3 * i + 2];
        atomicAdd(&h[regOf(binf(x), binf(y), binf(z))], 1);
    }
    __syncthreads();
    for (int i = threadIdx.x; i < NREG; i += blockDim.x)
        blockHist[blockIdx.x * NREG + i] = h[i];
    for (int i = blockIdx.x * blockDim.x + threadIdx.x; i < CELLS; i += stride)
        zeroB[i] = make_float4(0.f, 0.f, 0.f, 0.f);
}

// ---- pass A2: per-region column scan over blocks ----
__global__ void k_colscan(int* __restrict__ blockHist, int* __restrict__ regionPS) {
    int r = blockIdx.x * blockDim.x + threadIdx.x;
    if (r >= NREG) return;
    int run = 0;
    for (int b = 0; b < NB_A; ++b) {
        int idx = b * NREG + r;
        int v = blockHist[idx];
        blockHist[idx] = run;
        run += v;
    }
    regionPS[r] = run;
}

// ---- pass A3: exclusive prefix over 4096 region totals ----
__launch_bounds__(1024)
__global__ void k_regprefix(int* __restrict__ regionPS) {
    __shared__ int buf[1024];
    int t = threadIdx.x;
    int v0 = regionPS[4 * t + 0], v1 = regionPS[4 * t + 1];
    int v2 = regionPS[4 * t + 2], v3 = regionPS[4 * t + 3];
    int s = v0 + v1 + v2 + v3;
    buf[t] = s;
    __syncthreads();
    for (int d = 1; d < 1024; d <<= 1) {
        int add = (t >= d) ? buf[t - d] : 0;
        __syncthreads();
        buf[t] += add;
        __syncthreads();
    }
    int excl = buf[t] - s;
    regionPS[4 * t + 0] = excl;
    regionPS[4 * t + 1] = excl + v0;
    regionPS[4 * t + 2] = excl + v0 + v1;
    regionPS[4 * t + 3] = excl + v0 + v1 + v2;
    if (t == 1023) regionPS[4096] = buf[1023];
}

// ---- pass A4: scatter points into region buckets ----
__launch_bounds__(BLK)
__global__ void k_scatterA(const float* __restrict__ X, int n,
                           const int* __restrict__ blockHist,
                           const int* __restrict__ regionPS,
                           float4* __restrict__ bucket) {
    __shared__ int cur[NREG];
    for (int i = threadIdx.x; i < NREG; i += blockDim.x) cur[i] = 0;
    __syncthreads();
    int stride = gridDim.x * blockDim.x;
    for (int i = blockIdx.x * blockDim.x + threadIdx.x; i < n; i += stride) {
        float x = X[3 * i + 0], y = X[3 * i + 1], z = X[3 * i + 2];
        int r = regOf(binf(x), binf(y), binf(z));
        int pos = regionPS[r] + blockHist[blockIdx.x * NREG + r] + atomicAdd(&cur[r], 1);
        bucket[pos] = make_float4(x, y, z, __int_as_float(i));
    }
}

// ---- pass B: one block/region — LDS int-atomic accumulate, compact, PIdx ----
__launch_bounds__(BLK)
__global__ void k_binB(const float4* __restrict__ bucket, const int* __restrict__ regionPS,
                       float4* __restrict__ A, int* __restrict__ E0,
                       int* __restrict__ PIdx, int* __restrict__ gM0) {
    __shared__ unsigned long long aX[RC3], aY[RC3], aZ[RC3];
    __shared__ unsigned aC[RC3];
    __shared__ int cidx[RC3];
    __shared__ int cnt, cur, sBase;
    int r = blockIdx.x;
    for (int c = threadIdx.x; c < RC3; c += blockDim.x) {
        aX[c] = 0ull; aY[c] = 0ull; aZ[c] = 0ull; aC[c] = 0u;
    }
    if (threadIdx.x == 0) { cnt = 0; cur = 0; }
    __syncthreads();
    int start = regionPS[r], end = regionPS[r + 1];
    for (int i = start + threadIdx.x; i < end; i += blockDim.x) {
        float4 p = bucket[i];
        int lc = lcOf(binf(p.x), binf(p.y), binf(p.z));
        atomicAdd(&aX[lc], (unsigned long long)(long long)rintf(p.x * FPS));
        atomicAdd(&aY[lc], (unsigned long long)(long long)rintf(p.y * FPS));
        atomicAdd(&aZ[lc], (unsigned long long)(long long)rintf(p.z * FPS));
        atomicAdd(&aC[lc], 1u);
    }
    __syncthreads();
    int myc = 0;
    for (int c = threadIdx.x; c < RC3; c += blockDim.x)
        if (aC[c] > 0u) ++myc;
    if (myc) atomicAdd(&cnt, myc);
    __syncthreads();
    if (threadIdx.x == 0 && cnt > 0) sBase = atomicAdd(gM0, cnt);
    __syncthreads();
    int rx = r / (RDIM * RDIM), ry = (r / RDIM) % RDIM, rz = r % RDIM;
    for (int c = threadIdx.x; c < RC3; c += blockDim.x) {
        if (aC[c] > 0u) {
            int idx = sBase + atomicAdd(&cur, 1);
            cidx[c] = idx;
            int bx = rx * RC + c / (RC * RC);
            int by = ry * RC + (c / RC) % RC;
            int bz = rz * RC + c % RC;
            int b = flatb(bx, by, bz);
            E0[idx] = b;
            A[b] = make_float4((float)((double)(long long)aX[c] * FPSI),
                               (float)((double)(long long)aY[c] * FPSI),
                               (float)((double)(long long)aZ[c] * FPSI),
                               (float)aC[c]);
        }
    }
    __syncthreads();
    for (int i = start + threadIdx.x; i < end; i += blockDim.x) {
        float4 p = bucket[i];
        int lc = lcOf(binf(p.x), binf(p.y), binf(p.z));
        PIdx[__float_as_int(p.w)] = cidx[lc];
    }
}

// ---- fused per-step kernel; conv uses 8 lanes/item (16 taps each) ----
__launch_bounds__(BLK)
__global__ void k_fused(
    const float4* __restrict__ src, const int* __restrict__ list, const int* __restrict__ pK,
    float4* __restrict__ REo, int* __restrict__ IDXo, float4* __restrict__ eposInit,
    float4* __restrict__ tgt, unsigned* __restrict__ clT,
    int* __restrict__ listOut, int* __restrict__ pKout,
    int updS, const float* __restrict__ X, int n, const int* __restrict__ PIdx,
    const float4* __restrict__ REp, const int* __restrict__ IDXp,
    const int* __restrict__ pM0, float4* __restrict__ epos,
    unsigned* __restrict__ notConv,
    const int* __restrict__ clearList, const int* __restrict__ pKc,
    float4* __restrict__ clearGrid,
    unsigned* __restrict__ zeroMask, int zmW,
    float4* __restrict__ zeroGrid, int zgC, int lastStep) {
    __shared__ unsigned sFlag;
    if (threadIdx.x == 0) sFlag = 0;
    __syncthreads();
    int K = *pK;
    int KS = K * 8;                      // 8 slots per conv item (group-aligned)
    int U = (updS > 0) ? (X ? n : *pM0) : 0;
    int CL = clearList ? *pKc : 0;
    int total = KS + U + CL + zmW + zgC;
    bool done = false;
    if (updS > 1) {
        for (int t = 1; t < updS; ++t) done |= (notConv[t] == 0u);
    }
    int lane = threadIdx.x & 63;
    bool moved = false;
    int stride = gridDim.x * blockDim.x;
    for (int idx = blockIdx.x * blockDim.x + threadIdx.x; idx < total; idx += stride) {
        if (idx < KS) {
            int item = idx >> 3, sub = idx & 7;
            int b = list[item];
            int bx = b / DIM2, rem = b % DIM2;
            int by = rem / DIM, bz = rem % DIM;
            float sx = 0.f, sy = 0.f, sz = 0.f, sc = 0.f;
            int tb = sub * 16;
            #pragma unroll
            for (int j = 0; j < 16; ++j) {
                int t = tb + j;
                if (t < 125) {
                    int dx = t / 25, r2 = t % 25, dy = r2 / 5, dz = r2 % 5;
                    int ix = bx + dx - 2, iy = by + dy - 2, iz = bz + dz - 2;
                    bool ok = ((unsigned)ix < (unsigned)DIM) & ((unsigned)iy < (unsigned)DIM) &
                              ((unsigned)iz < (unsigned)DIM);
                    float w = ok ? (float)((3 - abs(dx - 2)) * (3 - abs(dy - 2)) * (3 - abs(dz - 2)))
                                 : 0.f;
                    float4 e = src[flatb(clampb(ix), clampb(iy), clampb(iz))];
                    sx = fmaf(w, e.x, sx);
                    sy = fmaf(w, e.y, sy);
                    sz = fmaf(w, e.z, sz);
                    sc = fmaf(w, e.w, sc);
                }
            }
            #pragma unroll
            for (int m = 1; m < 8; m <<= 1) {
                sx += __shfl_xor(sx, m, 8);
                sy += __shfl_xor(sy, m, 8);
                sz += __shfl_xor(sz, m, 8);
                sc += __shfl_xor(sc, m, 8);
            }
            if (sub == 0) {
                float W = src[b].w;      // center count (cell occupied => sc>0)
                float4 np = make_float4(sx / sc, sy / sc, sz / sc, W);
                REo[item] = np;
                IDXo[b] = item;
                if (eposInit) eposInit[item] = np;
                if (!lastStep) {
                    int bn = flatb(binf(np.x), binf(np.y), binf(np.z));
                    float* cell = (float*)&tgt[bn];
                    pk_add(cell + 0, W * np.x, W * np.y);
                    pk_add(cell + 2, W * np.z, W);
                    unsigned old = atomicOr(&clT[(unsigned)bn >> 5], 1u << (bn & 31));
                    bool isNew = !(old & (1u << (bn & 31)));
                    unsigned long long m = __ballot(isNew);
                    if (m) {
                        int leader = (int)__ffsll((long long)m) - 1;
                        int base;
                        if (lane == leader) base = atomicAdd(pKout, __popcll(m));
                        base = __shfl(base, leader, 64);
                        if (isNew) listOut[base + __popcll(m & ((1ull << lane) - 1))] = bn;
                    }
                }
            }
        } else if (idx < KS + U) {
            int e = idx - KS;
            if (X) {  // per-point step-1 convergence via PIdx
                float x = X[3 * e + 0], y = X[3 * e + 1], z = X[3 * e + 2];
                float4 rr = REp[PIdx[e]];
                float ex = rr.x - x, ey = rr.y - y, ez = rr.z - z;
                moved |= (fmaf(ex, ex, fmaf(ey, ey, ez * ez)) > TOL2);
            } else if (!done) {  // per-entry update to step-updS position
                float4 p = epos[e];
                int j = IDXp[flatb(binf(p.x), binf(p.y), binf(p.z))];
                float4 rr = REp[j];
                float ex = rr.x - p.x, ey = rr.y - p.y, ez = rr.z - p.z;
                moved |= (fmaf(ex, ex, fmaf(ey, ey, ez * ez)) > TOL2);
                epos[e] = make_float4(rr.x, rr.y, rr.z, p.w);
            }
        } else if (idx < KS + U + CL) {
            clearGrid[clearList[idx - KS - U]] = make_float4(0.f, 0.f, 0.f, 0.f);
        } else if (idx < KS + U + CL + zmW) {
            zeroMask[idx - KS - U - CL] = 0u;
        } else {
            zeroGrid[idx - KS - U - CL - zmW] = make_float4(0.f, 0.f, 0.f, 0.f);
        }
    }
    if (moved) sFlag = 1;
    __syncthreads();
    if (threadIdx.x == 0 && updS > 0 && sFlag) notConv[updS] = 1u;
}

// NOTE: REo is now indexed by ITEM (entry), IDXo[b] -> item; consumers use
// REp[IDXp[bin]] which is unchanged, and step-1 consumers use REp[PIdx[e]]
// (PIdx indexes F1's item order == E0 order). k_fin uses IDXa lookups.

// ---- finalize: per-entry final position table fpos[e] ----
__launch_bounds__(BLK)
__global__ void k_fin(const float4* __restrict__ REa, const int* __restrict__ IDXa,
                      const float4* __restrict__ epos, const int* __restrict__ pM0,
                      const unsigned* __restrict__ notConv, float4* __restrict__ fpos) {
    int M0 = *pM0;
    bool done = false;
    for (int t = 1; t <= 4; ++t) done |= (notConv[t] == 0u);
    for (int e = blockIdx.x * blockDim.x + threadIdx.x; e < M0;
         e += gridDim.x * blockDim.x) {
        float4 p = epos[e];
        if (!done) {
            float4 rr = REa[IDXa[flatb(binf(p.x), binf(p.y), binf(p.z))]];
            p.x = rr.x; p.y = rr.y; p.z = rr.z;
        }
        fpos[e] = p;
    }
}

// ---- per-point output: single gather through fpos via PIdx ----
__global__ void k_map(const int* __restrict__ PIdx, int n, const float4* __restrict__ fpos,
                      float* __restrict__ out) {
    int i = blockIdx.x * blockDim.x + threadIdx.x;
    if (i >= n) return;
    float4 p = fpos[PIdx[i]];
    out[3 * i + 0] = p.x;
    out[3 * i + 1] = p.y;
    out[3 * i + 2] = p.z;
}

extern "C" void kernel_launch(void* const* d_in, const int* in_sizes, int n_in,
                              void* d_out, int out_size, void* d_ws, size_t ws_size,
                              hipStream_t stream) {
    const float* X = (const float*)d_in[0];
    int n = in_sizes[0] / 3;

    char* ws = (char*)d_ws;
    int*      cnt     = (int*)ws;        // cnt[1..5] list sizes
    unsigned* notConv = (unsigned*)(ws + 32);
    size_t mB = (size_t)CLW * 4;
    size_t gB = (size_t)CELLS * 16;
    unsigned* m0 = (unsigned*)(ws + 256);
    unsigned* m1 = (unsigned*)(ws + 256 + mB);
    float4* A = (float4*)(ws + 256 + 2 * mB);
    float4* B = (float4*)((char*)A + gB);
    float4* C = (float4*)((char*)B + gB);
    int* IDXa = (int*)((char*)C + gB);
    int* IDXb = IDXa + CELLS;
    float4* REa  = (float4*)(IDXb + CELLS);
    float4* REb  = REa + n;
    float4* epos = REb + n;
    int* E0   = (int*)(epos + n);
    int* La   = E0 + n;
    int* Lb   = La + n;
    int* Lc   = Lb + n;
    int* PIdx = Lc + n;
    float4* bucket = (float4*)(PIdx + n);
    int* blockHist = (int*)(bucket + n);
    int* regionPS  = blockHist + NB_A * NREG;

    hipMemsetAsync(ws, 0, 256 + 2 * mB + gB, stream);  // meta+masks+A

    k_histA<<<NB_A, BLK, 0, stream>>>(X, n, blockHist, B);
    k_colscan<<<NREG / BLK, BLK, 0, stream>>>(blockHist, regionPS);
    k_regprefix<<<1, 1024, 0, stream>>>(regionPS);
    k_scatterA<<<NB_A, BLK, 0, stream>>>(X, n, blockHist, regionPS, bucket);
    k_binB<<<NREG, BLK, 0, stream>>>(bucket, regionPS, A, E0, PIdx, &cnt[1]);

    const int NF = 2048;
    // F1: conv A/E0 -> REa/IDXa (+epos init); scatter->B (m0 -> La); zero C
    k_fused<<<NF, BLK, 0, stream>>>(A, E0, &cnt[1], REa, IDXa, epos,
                                    B, m0, La, &cnt[2],
                                    0, nullptr, n, nullptr, nullptr, nullptr, nullptr,
                                    nullptr, notConv, nullptr, nullptr, nullptr,
                                    nullptr, 0, C, CELLS, 0);
    // F2: conv B/La -> REb/IDXb; scatter->C (m1 -> Lb); upd1 via PIdx (REa);
    //     clear A via E0; zero m0
    k_fused<<<NF, BLK, 0, stream>>>(B, La, &cnt[2], REb, IDXb, nullptr,
                                    C, m1, Lb, &cnt[3],
                                    1, X, n, PIdx, REa, IDXa, &cnt[1], nullptr,
                                    notConv, E0, &cnt[1], A,
                                    m0, CLW, nullptr, 0, 0);
    // F3: conv C/Lb -> REa/IDXa; scatter->A (m0 -> Lc); upd2 (REb/IDXb);
    //     clear B via La; zero m1
    k_fused<<<NF, BLK, 0, stream>>>(C, Lb, &cnt[3], REa, IDXa, nullptr,
                                    A, m0, Lc, &cnt[4],
                                    2, nullptr, n, nullptr, REb, IDXb, &cnt[1], epos,
                                    notConv, La, &cnt[2], B,
                                    m1, CLW, nullptr, 0, 0);
    // F4: conv A/Lc -> REb/IDXb; scatter->B (m1 -> La); upd3 (REa/IDXa)
    k_fused<<<NF, BLK, 0, stream>>>(A, Lc, &cnt[4], REb, IDXb, nullptr,
                                    B, m1, La, &cnt[5],
                                    3, nullptr, n, nullptr, REa, IDXa, &cnt[1], epos,
                                    notConv, nullptr, nullptr, nullptr,
                                    nullptr, 0, nullptr, 0, 0);
    // F5: conv B/La -> REa/IDXa (conv only); upd4 (REb/IDXb)
    k_fused<<<NF, BLK, 0, stream>>>(B, La, &cnt[5], REa, IDXa, nullptr,
                                    nullptr, nullptr, nullptr, nullptr,
                                    4, nullptr, n, nullptr, REb, IDXb, &cnt[1], epos,
                                    notConv, nullptr, nullptr, nullptr,
                                    nullptr, 0, nullptr, 0, 1);

    k_fin<<<256, BLK, 0, stream>>>(REa, IDXa, epos, &cnt[1], notConv, REb);
    k_map<<<(n + BLK - 1) / BLK, BLK, 0, stream>>>(PIdx, n, REb, (float*)d_out);
}

// Round 9
// 284.868 us; speedup vs baseline: 2.0152x; 2.0152x over previous
//
#include <hip/hip_runtime.h>

// MeanShift++ dense-grid, distinct-bin formulation, v7.
// Identity 1: ref pipeline == 5-tap triangular conv [1,2,3,2,1]^3 over per-bin
// sums/counts. Identity 2: result depends only on bin => per-step work is per
// OCCUPIED BIN; per-point state via 1-tap lookups.
// v7 (vs v6 which regressed 3x): conv split 5 threads/item by dx-PLANE, each
// thread keeps r7's row-contiguous dy/dz loop (clean codegen: row base +
// immediate offsets), partials reduced through LDS (plain store + barrier),
// NO lane shuffles, NO flattened tap addressing. Conv is block-structured
// (51 items/block, blockIdx < BC); misc segments on the remaining blocks.

constexpr float BW   = 0.1f;
constexpr float TOL2 = 1e-6f;            // (1e-3)^2
constexpr int DIM  = 112, OFF = 56;      // bins in [-56,55]; |x|<5.6 covered
constexpr int DIM2 = DIM * DIM;
constexpr int CELLS = DIM * DIM * DIM;   // 1,404,928
constexpr int CLW = CELLS / 32;
constexpr int RDIM = 16, RC = 7;         // 16^3 regions of 7^3 cells
constexpr int NREG = RDIM * RDIM * RDIM; // 4096
constexpr int RC3 = RC * RC * RC;        // 343
constexpr int NB_A = 128, BLK = 256;
constexpr int NF = 2048;                 // k_fused grid
constexpr int IPB = 51;                  // conv items per block (51*5=255 thr)
constexpr float FPS = 16777216.0f;       // 2^24 fixed-point scale
constexpr double FPSI = 1.0 / 16777216.0;

typedef float vf2 __attribute__((ext_vector_type(2)));

__device__ __forceinline__ int clampb(int v) { return v < 0 ? 0 : (v > DIM - 1 ? DIM - 1 : v); }
__device__ __forceinline__ int binf(float v) { return clampb((int)(v / BW) + OFF); }  // IEEE div+trunc == ref
__device__ __forceinline__ int flatb(int bx, int by, int bz) { return (bx * DIM + by) * DIM + bz; }
__device__ __forceinline__ int regOf(int bx, int by, int bz) {
    return ((bx / RC) * RDIM + (by / RC)) * RDIM + (bz / RC);
}
__device__ __forceinline__ int lcOf(int bx, int by, int bz) {
    return ((bx % RC) * RC + (by % RC)) * RC + (bz % RC);
}

__device__ __forceinline__ void pk_add(float* p, float a, float b) {
#if defined(__has_builtin) && __has_builtin(__builtin_amdgcn_global_atomic_fadd_v2f32)
    vf2 v = {a, b};
    __builtin_amdgcn_global_atomic_fadd_v2f32((vf2*)p, v);
#else
    atomicAdd(p, a);
    atomicAdd(p + 1, b);
#endif
}

// ---- pass A1: per-block region histogram (LDS) + streaming zero of grid B ----
__launch_bounds__(BLK)
__global__ void k_histA(const float* __restrict__ X, int n, int* __restrict__ blockHist,
                        float4* __restrict__ zeroB) {
    __shared__ int h[NREG];
    for (int i = threadIdx.x; i < NREG; i += blockDim.x) h[i] = 0;
    __syncthreads();
    int stride = gridDim.x * blockDim.x;
    for (int i = blockIdx.x * blockDim.x + threadIdx.x; i < n; i += stride) {
        float x = X[3 * i + 0], y = X[3 * i + 1], z = X[3 * i + 2];
        atomicAdd(&h[regOf(binf(x), binf(y), binf(z))], 1);
    }
    __syncthreads();
    for (int i = threadIdx.x; i < NREG; i += blockDim.x)
        blockHist[blockIdx.x * NREG + i] = h[i];
    for (int i = blockIdx.x * blockDim.x + threadIdx.x; i < CELLS; i += stride)
        zeroB[i] = make_float4(0.f, 0.f, 0.f, 0.f);
}

// ---- pass A2: per-region column scan over blocks ----
__global__ void k_colscan(int* __restrict__ blockHist, int* __restrict__ regionPS) {
    int r = blockIdx.x * blockDim.x + threadIdx.x;
    if (r >= NREG) return;
    int run = 0;
    for (int b = 0; b < NB_A; ++b) {
        int idx = b * NREG + r;
        int v = blockHist[idx];
        blockHist[idx] = run;
        run += v;
    }
    regionPS[r] = run;
}

// ---- pass A3: exclusive prefix over 4096 region totals ----
__launch_bounds__(1024)
__global__ void k_regprefix(int* __restrict__ regionPS) {
    __shared__ int buf[1024];
    int t = threadIdx.x;
    int v0 = regionPS[4 * t + 0], v1 = regionPS[4 * t + 1];
    int v2 = regionPS[4 * t + 2], v3 = regionPS[4 * t + 3];
    int s = v0 + v1 + v2 + v3;
    buf[t] = s;
    __syncthreads();
    for (int d = 1; d < 1024; d <<= 1) {
        int add = (t >= d) ? buf[t - d] : 0;
        __syncthreads();
        buf[t] += add;
        __syncthreads();
    }
    int excl = buf[t] - s;
    regionPS[4 * t + 0] = excl;
    regionPS[4 * t + 1] = excl + v0;
    regionPS[4 * t + 2] = excl + v0 + v1;
    regionPS[4 * t + 3] = excl + v0 + v1 + v2;
    if (t == 1023) regionPS[4096] = buf[1023];
}

// ---- pass A4: scatter points into region buckets ----
__launch_bounds__(BLK)
__global__ void k_scatterA(const float* __restrict__ X, int n,
                           const int* __restrict__ blockHist,
                           const int* __restrict__ regionPS,
                           float4* __restrict__ bucket) {
    __shared__ int cur[NREG];
    for (int i = threadIdx.x; i < NREG; i += blockDim.x) cur[i] = 0;
    __syncthreads();
    int stride = gridDim.x * blockDim.x;
    for (int i = blockIdx.x * blockDim.x + threadIdx.x; i < n; i += stride) {
        float x = X[3 * i + 0], y = X[3 * i + 1], z = X[3 * i + 2];
        int r = regOf(binf(x), binf(y), binf(z));
        int pos = regionPS[r] + blockHist[blockIdx.x * NREG + r] + atomicAdd(&cur[r], 1);
        bucket[pos] = make_float4(x, y, z, __int_as_float(i));
    }
}

// ---- pass B: one block/region — LDS int-atomic accumulate, compact, PIdx ----
__launch_bounds__(BLK)
__global__ void k_binB(const float4* __restrict__ bucket, const int* __restrict__ regionPS,
                       float4* __restrict__ A, int* __restrict__ E0,
                       int* __restrict__ PIdx, int* __restrict__ gM0) {
    __shared__ unsigned long long aX[RC3], aY[RC3], aZ[RC3];
    __shared__ unsigned aC[RC3];
    __shared__ int cidx[RC3];
    __shared__ int cnt, cur, sBase;
    int r = blockIdx.x;
    for (int c = threadIdx.x; c < RC3; c += blockDim.x) {
        aX[c] = 0ull; aY[c] = 0ull; aZ[c] = 0ull; aC[c] = 0u;
    }
    if (threadIdx.x == 0) { cnt = 0; cur = 0; }
    __syncthreads();
    int start = regionPS[r], end = regionPS[r + 1];
    for (int i = start + threadIdx.x; i < end; i += blockDim.x) {
        float4 p = bucket[i];
        int lc = lcOf(binf(p.x), binf(p.y), binf(p.z));
        atomicAdd(&aX[lc], (unsigned long long)(long long)rintf(p.x * FPS));
        atomicAdd(&aY[lc], (unsigned long long)(long long)rintf(p.y * FPS));
        atomicAdd(&aZ[lc], (unsigned long long)(long long)rintf(p.z * FPS));
        atomicAdd(&aC[lc], 1u);
    }
    __syncthreads();
    int myc = 0;
    for (int c = threadIdx.x; c < RC3; c += blockDim.x)
        if (aC[c] > 0u) ++myc;
    if (myc) atomicAdd(&cnt, myc);
    __syncthreads();
    if (threadIdx.x == 0 && cnt > 0) sBase = atomicAdd(gM0, cnt);
    __syncthreads();
    int rx = r / (RDIM * RDIM), ry = (r / RDIM) % RDIM, rz = r % RDIM;
    for (int c = threadIdx.x; c < RC3; c += blockDim.x) {
        if (aC[c] > 0u) {
            int idx = sBase + atomicAdd(&cur, 1);
            cidx[c] = idx;
            int bx = rx * RC + c / (RC * RC);
            int by = ry * RC + (c / RC) % RC;
            int bz = rz * RC + c % RC;
            int b = flatb(bx, by, bz);
            E0[idx] = b;
            A[b] = make_float4((float)((double)(long long)aX[c] * FPSI),
                               (float)((double)(long long)aY[c] * FPSI),
                               (float)((double)(long long)aZ[c] * FPSI),
                               (float)aC[c]);
        }
    }
    __syncthreads();
    for (int i = start + threadIdx.x; i < end; i += blockDim.x) {
        float4 p = bucket[i];
        int lc = lcOf(binf(p.x), binf(p.y), binf(p.z));
        PIdx[__float_as_int(p.w)] = cidx[lc];
    }
}

// ---- fused per-step kernel ----
// Blocks [0, BC): conv, 51 items/block, 5 threads/item (one dx-plane each),
//   r7-style row-contiguous taps, LDS reduce, finalize+scatter by lanes 0..50.
// Blocks [BC, NF): grid-stride misc segments (upd / clear / mask-zero / grid-zero).
__launch_bounds__(BLK)
__global__ void k_fused(
    const float4* __restrict__ src, const int* __restrict__ list, const int* __restrict__ pK,
    float4* __restrict__ REo, int* __restrict__ IDXo, float4* __restrict__ eposInit,
    float4* __restrict__ tgt, unsigned* __restrict__ clT,
    int* __restrict__ listOut, int* __restrict__ pKout,
    int updS, const float* __restrict__ X, int n, const int* __restrict__ PIdx,
    const float4* __restrict__ REp, const int* __restrict__ IDXp,
    const int* __restrict__ pM0, float4* __restrict__ epos,
    unsigned* __restrict__ notConv,
    const int* __restrict__ clearList, const int* __restrict__ pKc,
    float4* __restrict__ clearGrid,
    unsigned* __restrict__ zeroMask, int zmW,
    float4* __restrict__ zeroGrid, int zgC, int lastStep) {
    __shared__ float4 sh[BLK];
    __shared__ unsigned sFlag;
    if (threadIdx.x == 0) sFlag = 0;
    __syncthreads();
    int K = *pK;
    int BC = (K + IPB - 1) / IPB;
    if (BC > NF - 256) BC = NF - 256;    // always keep misc blocks
    const float t5[5] = {1.f, 2.f, 3.f, 2.f, 1.f};
    int lane = threadIdx.x & 63;
    bool moved = false;

    if ((int)blockIdx.x < BC) {
        // ---------------- conv blocks ----------------
        for (int ib = blockIdx.x; ib * IPB < K; ib += BC) {
            int li = threadIdx.x / 5;        // 0..51 (255 -> 51, guarded)
            int dx = threadIdx.x % 5;
            int item = ib * IPB + li;
            float4 part = make_float4(0.f, 0.f, 0.f, 0.f);
            if (li < IPB && item < K) {
                int b = list[item];
                int bx = b / DIM2, rem = b % DIM2;
                int by = rem / DIM, bz = rem % DIM;
                int ix = bx + dx - 2;
                if ((unsigned)ix < (unsigned)DIM) {
                    float wx = t5[dx];
                    if (by >= 2 && by <= DIM - 3 && bz >= 2 && bz <= DIM - 3) {
                        #pragma unroll
                        for (int dy = 0; dy < 5; ++dy) {
                            float wxy = wx * t5[dy];
                            const float4* row = src + flatb(ix, by + dy - 2, bz - 2);
                            #pragma unroll
                            for (int dz = 0; dz < 5; ++dz) {
                                float w = wxy * t5[dz];
                                float4 e = row[dz];
                                part.x = fmaf(w, e.x, part.x);
                                part.y = fmaf(w, e.y, part.y);
                                part.z = fmaf(w, e.z, part.z);
                                part.w = fmaf(w, e.w, part.w);
                            }
                        }
                    } else {
                        for (int dy = 0; dy < 5; ++dy) {
                            int iy = by + dy - 2;
                            if ((unsigned)iy >= (unsigned)DIM) continue;
                            float wxy = wx * t5[dy];
                            for (int dz = 0; dz < 5; ++dz) {
                                int iz = bz + dz - 2;
                                if ((unsigned)iz >= (unsigned)DIM) continue;
                                float w = wxy * t5[dz];
                                float4 e = src[flatb(ix, iy, iz)];
                                part.x = fmaf(w, e.x, part.x);
                                part.y = fmaf(w, e.y, part.y);
                                part.z = fmaf(w, e.z, part.z);
                                part.w = fmaf(w, e.w, part.w);
                            }
                        }
                    }
                }
            }
            sh[threadIdx.x] = part;
            __syncthreads();
            if (threadIdx.x < IPB) {
                int item2 = ib * IPB + threadIdx.x;
                if (item2 < K) {
                    int base5 = threadIdx.x * 5;
                    float4 a0 = sh[base5 + 0], a1 = sh[base5 + 1], a2 = sh[base5 + 2];
                    float4 a3 = sh[base5 + 3], a4 = sh[base5 + 4];
                    float sx = a0.x + a1.x + a2.x + a3.x + a4.x;
                    float sy = a0.y + a1.y + a2.y + a3.y + a4.y;
                    float sz = a0.z + a1.z + a2.z + a3.z + a4.z;
                    float sc = a0.w + a1.w + a2.w + a3.w + a4.w;
                    int b = list[item2];
                    float W = src[b].w;     // center count (occupied => sc>0)
                    float4 np = make_float4(sx / sc, sy / sc, sz / sc, W);
                    REo[item2] = np;
                    IDXo[b] = item2;
                    if (eposInit) eposInit[item2] = np;
                    if (!lastStep) {
                        int bn = flatb(binf(np.x), binf(np.y), binf(np.z));
                        float* cell = (float*)&tgt[bn];
                        pk_add(cell + 0, W * np.x, W * np.y);
                        pk_add(cell + 2, W * np.z, W);
                        unsigned old = atomicOr(&clT[(unsigned)bn >> 5], 1u << (bn & 31));
                        bool isNew = !(old & (1u << (bn & 31)));
                        unsigned long long m = __ballot(isNew);
                        if (m) {
                            int leader = (int)__ffsll((long long)m) - 1;
                            int base;
                            if (lane == leader) base = atomicAdd(pKout, __popcll(m));
                            base = __shfl(base, leader, 64);
                            if (isNew) listOut[base + __popcll(m & ((1ull << lane) - 1))] = bn;
                        }
                    }
                }
            }
            __syncthreads();    // sh reuse
        }
    } else {
        // ---------------- misc blocks ----------------
        int U = (updS > 0) ? (X ? n : *pM0) : 0;
        int CL = clearList ? *pKc : 0;
        int total = U + CL + zmW + zgC;
        bool done = false;
        if (updS > 1) {
            for (int t = 1; t < updS; ++t) done |= (notConv[t] == 0u);
        }
        int stride = (NF - BC) * blockDim.x;
        for (int idx = (blockIdx.x - BC) * blockDim.x + threadIdx.x; idx < total;
             idx += stride) {
            if (idx < U) {
                int e = idx;
                if (X) {  // per-point step-1 convergence via PIdx
                    float x = X[3 * e + 0], y = X[3 * e + 1], z = X[3 * e + 2];
                    float4 rr = REp[PIdx[e]];
                    float ex = rr.x - x, ey = rr.y - y, ez = rr.z - z;
                    moved |= (fmaf(ex, ex, fmaf(ey, ey, ez * ez)) > TOL2);
                } else if (!done) {  // per-entry update to step-updS position
                    float4 p = epos[e];
                    int j = IDXp[flatb(binf(p.x), binf(p.y), binf(p.z))];
                    float4 rr = REp[j];
                    float ex = rr.x - p.x, ey = rr.y - p.y, ez = rr.z - p.z;
                    moved |= (fmaf(ex, ex, fmaf(ey, ey, ez * ez)) > TOL2);
                    epos[e] = make_float4(rr.x, rr.y, rr.z, p.w);
                }
            } else if (idx < U + CL) {
                clearGrid[clearList[idx - U]] = make_float4(0.f, 0.f, 0.f, 0.f);
            } else if (idx < U + CL + zmW) {
                zeroMask[idx - U - CL] = 0u;
            } else {
                zeroGrid[idx - U - CL - zmW] = make_float4(0.f, 0.f, 0.f, 0.f);
            }
        }
    }
    if (moved) sFlag = 1;
    __syncthreads();
    if (threadIdx.x == 0 && updS > 0 && sFlag) notConv[updS] = 1u;
}

// ---- finalize: per-entry final position table fpos[e] ----
__launch_bounds__(BLK)
__global__ void k_fin(const float4* __restrict__ REa, const int* __restrict__ IDXa,
                      const float4* __restrict__ epos, const int* __restrict__ pM0,
                      const unsigned* __restrict__ notConv, float4* __restrict__ fpos) {
    int M0 = *pM0;
    bool done = false;
    for (int t = 1; t <= 4; ++t) done |= (notConv[t] == 0u);
    for (int e = blockIdx.x * blockDim.x + threadIdx.x; e < M0;
         e += gridDim.x * blockDim.x) {
        float4 p = epos[e];
        if (!done) {
            float4 rr = REa[IDXa[flatb(binf(p.x), binf(p.y), binf(p.z))]];
            p.x = rr.x; p.y = rr.y; p.z = rr.z;
        }
        fpos[e] = p;
    }
}

// ---- per-point output: single gather through fpos via PIdx ----
__global__ void k_map(const int* __restrict__ PIdx, int n, const float4* __restrict__ fpos,
                      float* __restrict__ out) {
    int i = blockIdx.x * blockDim.x + threadIdx.x;
    if (i >= n) return;
    float4 p = fpos[PIdx[i]];
    out[3 * i + 0] = p.x;
    out[3 * i + 1] = p.y;
    out[3 * i + 2] = p.z;
}

extern "C" void kernel_launch(void* const* d_in, const int* in_sizes, int n_in,
                              void* d_out, int out_size, void* d_ws, size_t ws_size,
                              hipStream_t stream) {
    const float* X = (const float*)d_in[0];
    int n = in_sizes[0] / 3;

    char* ws = (char*)d_ws;
    int*      cnt     = (int*)ws;        // cnt[1..5] list sizes
    unsigned* notConv = (unsigned*)(ws + 32);
    size_t mB = (size_t)CLW * 4;
    size_t gB = (size_t)CELLS * 16;
    unsigned* m0 = (unsigned*)(ws + 256);
    unsigned* m1 = (unsigned*)(ws + 256 + mB);
    float4* A = (float4*)(ws + 256 + 2 * mB);
    float4* B = (float4*)((char*)A + gB);
    float4* C = (float4*)((char*)B + gB);
    int* IDXa = (int*)((char*)C + gB);
    int* IDXb = IDXa + CELLS;
    float4* REa  = (float4*)(IDXb + CELLS);
    float4* REb  = REa + n;
    float4* epos = REb + n;
    int* E0   = (int*)(epos + n);
    int* La   = E0 + n;
    int* Lb   = La + n;
    int* Lc   = Lb + n;
    int* PIdx = Lc + n;
    float4* bucket = (float4*)(PIdx + n);
    int* blockHist = (int*)(bucket + n);
    int* regionPS  = blockHist + NB_A * NREG;

    hipMemsetAsync(ws, 0, 256 + 2 * mB + gB, stream);  // meta+masks+A

    k_histA<<<NB_A, BLK, 0, stream>>>(X, n, blockHist, B);
    k_colscan<<<NREG / BLK, BLK, 0, stream>>>(blockHist, regionPS);
    k_regprefix<<<1, 1024, 0, stream>>>(regionPS);
    k_scatterA<<<NB_A, BLK, 0, stream>>>(X, n, blockHist, regionPS, bucket);
    k_binB<<<NREG, BLK, 0, stream>>>(bucket, regionPS, A, E0, PIdx, &cnt[1]);

    // F1: conv A/E0 -> REa/IDXa (+epos init); scatter->B (m0 -> La); zero C
    k_fused<<<NF, BLK, 0, stream>>>(A, E0, &cnt[1], REa, IDXa, epos,
                                    B, m0, La, &cnt[2],
                                    0, nullptr, n, nullptr, nullptr, nullptr, nullptr,
                                    nullptr, notConv, nullptr, nullptr, nullptr,
                                    nullptr, 0, C, CELLS, 0);
    // F2: conv B/La -> REb/IDXb; scatter->C (m1 -> Lb); upd1 via PIdx (REa);
    //     clear A via E0; zero m0
    k_fused<<<NF, BLK, 0, stream>>>(B, La, &cnt[2], REb, IDXb, nullptr,
                                    C, m1, Lb, &cnt[3],
                                    1, X, n, PIdx, REa, IDXa, &cnt[1], nullptr,
                                    notConv, E0, &cnt[1], A,
                                    m0, CLW, nullptr, 0, 0);
    // F3: conv C/Lb -> REa/IDXa; scatter->A (m0 -> Lc); upd2 (REb/IDXb);
    //     clear B via La; zero m1
    k_fused<<<NF, BLK, 0, stream>>>(C, Lb, &cnt[3], REa, IDXa, nullptr,
                                    A, m0, Lc, &cnt[4],
                                    2, nullptr, n, nullptr, REb, IDXb, &cnt[1], epos,
                                    notConv, La, &cnt[2], B,
                                    m1, CLW, nullptr, 0, 0);
    // F4: conv A/Lc -> REb/IDXb; scatter->B (m1 -> La); upd3 (REa/IDXa)
    k_fused<<<NF, BLK, 0, stream>>>(A, Lc, &cnt[4], REb, IDXb, nullptr,
                                    B, m1, La, &cnt[5],
                                    3, nullptr, n, nullptr, REa, IDXa, &cnt[1], epos,
                                    notConv, nullptr, nullptr, nullptr,
                                    nullptr, 0, nullptr, 0, 0);
    // F5: conv B/La -> REa/IDXa (conv only); upd4 (REb/IDXb)
    k_fused<<<NF, BLK, 0, stream>>>(B, La, &cnt[5], REa, IDXa, nullptr,
                                    nullptr, nullptr, nullptr, nullptr,
                                    4, nullptr, n, nullptr, REb, IDXb, &cnt[1], epos,
                                    notConv, nullptr, nullptr, nullptr,
                                    nullptr, 0, nullptr, 0, 1);

    k_fin<<<256, BLK, 0, stream>>>(REa, IDXa, epos, &cnt[1], notConv, REb);
    k_map<<<(n + BLK - 1) / BLK, BLK, 0, stream>>>(PIdx, n, REb, (float*)d_out);
}

// Round 10
// 253.046 us; speedup vs baseline: 2.2686x; 1.1258x over previous
//
#include <hip/hip_runtime.h>

// MeanShift++ dense-grid, distinct-bin formulation, v8.
// Identity 1: ref pipeline == 5-tap triangular conv [1,2,3,2,1]^3 over per-bin
// sums/counts. Identity 2: result depends only on bin => per-step work is per
// OCCUPIED BIN; per-point state via 1-tap lookups.
// v8 (vs v9-run=285us): conv lists are now BIN-SORTED — claim masks are
// compacted by a dedicated k_compactM between steps (block scan, 1 atomic per
// block, clears mask in passing) instead of wave-appended in discovery order.
// r9 counters showed F-kernels pinned at hbm_bytes/~490GB/s: random-order
// lists defeated row reuse. Also: grid-C zero moved off F1 into k_scatterA.

constexpr float BW   = 0.1f;
constexpr float TOL2 = 1e-6f;            // (1e-3)^2
constexpr int DIM  = 112, OFF = 56;      // bins in [-56,55]; |x|<5.6 covered
constexpr int DIM2 = DIM * DIM;
constexpr int CELLS = DIM * DIM * DIM;   // 1,404,928
constexpr int CLW = CELLS / 32;          // 43,904 mask words
constexpr int RDIM = 16, RC = 7;         // 16^3 regions of 7^3 cells
constexpr int NREG = RDIM * RDIM * RDIM; // 4096
constexpr int RC3 = RC * RC * RC;        // 343
constexpr int NB_A = 128, BLK = 256;
constexpr int NF = 2048;                 // k_fused grid
constexpr int IPB = 51;                  // conv items per block (51*5=255 thr)
constexpr float FPS = 16777216.0f;       // 2^24 fixed-point scale
constexpr double FPSI = 1.0 / 16777216.0;

typedef float vf2 __attribute__((ext_vector_type(2)));

__device__ __forceinline__ int clampb(int v) { return v < 0 ? 0 : (v > DIM - 1 ? DIM - 1 : v); }
__device__ __forceinline__ int binf(float v) { return clampb((int)(v / BW) + OFF); }  // IEEE div+trunc == ref
__device__ __forceinline__ int flatb(int bx, int by, int bz) { return (bx * DIM + by) * DIM + bz; }
__device__ __forceinline__ int regOf(int bx, int by, int bz) {
    return ((bx / RC) * RDIM + (by / RC)) * RDIM + (bz / RC);
}
__device__ __forceinline__ int lcOf(int bx, int by, int bz) {
    return ((bx % RC) * RC + (by % RC)) * RC + (bz % RC);
}

__device__ __forceinline__ void pk_add(float* p, float a, float b) {
#if defined(__has_builtin) && __has_builtin(__builtin_amdgcn_global_atomic_fadd_v2f32)
    vf2 v = {a, b};
    __builtin_amdgcn_global_atomic_fadd_v2f32((vf2*)p, v);
#else
    atomicAdd(p, a);
    atomicAdd(p + 1, b);
#endif
}

// ---- pass A1: per-block region histogram (LDS) + streaming zero of grid B ----
__launch_bounds__(BLK)
__global__ void k_histA(const float* __restrict__ X, int n, int* __restrict__ blockHist,
                        float4* __restrict__ zeroB) {
    __shared__ int h[NREG];
    for (int i = threadIdx.x; i < NREG; i += blockDim.x) h[i] = 0;
    __syncthreads();
    int stride = gridDim.x * blockDim.x;
    for (int i = blockIdx.x * blockDim.x + threadIdx.x; i < n; i += stride) {
        float x = X[3 * i + 0], y = X[3 * i + 1], z = X[3 * i + 2];
        atomicAdd(&h[regOf(binf(x), binf(y), binf(z))], 1);
    }
    __syncthreads();
    for (int i = threadIdx.x; i < NREG; i += blockDim.x)
        blockHist[blockIdx.x * NREG + i] = h[i];
    for (int i = blockIdx.x * blockDim.x + threadIdx.x; i < CELLS; i += stride)
        zeroB[i] = make_float4(0.f, 0.f, 0.f, 0.f);
}

// ---- pass A2: per-region column scan over blocks ----
__global__ void k_colscan(int* __restrict__ blockHist, int* __restrict__ regionPS) {
    int r = blockIdx.x * blockDim.x + threadIdx.x;
    if (r >= NREG) return;
    int run = 0;
    for (int b = 0; b < NB_A; ++b) {
        int idx = b * NREG + r;
        int v = blockHist[idx];
        blockHist[idx] = run;
        run += v;
    }
    regionPS[r] = run;
}

// ---- pass A3: exclusive prefix over 4096 region totals ----
__launch_bounds__(1024)
__global__ void k_regprefix(int* __restrict__ regionPS) {
    __shared__ int buf[1024];
    int t = threadIdx.x;
    int v0 = regionPS[4 * t + 0], v1 = regionPS[4 * t + 1];
    int v2 = regionPS[4 * t + 2], v3 = regionPS[4 * t + 3];
    int s = v0 + v1 + v2 + v3;
    buf[t] = s;
    __syncthreads();
    for (int d = 1; d < 1024; d <<= 1) {
        int add = (t >= d) ? buf[t - d] : 0;
        __syncthreads();
        buf[t] += add;
        __syncthreads();
    }
    int excl = buf[t] - s;
    regionPS[4 * t + 0] = excl;
    regionPS[4 * t + 1] = excl + v0;
    regionPS[4 * t + 2] = excl + v0 + v1;
    regionPS[4 * t + 3] = excl + v0 + v1 + v2;
    if (t == 1023) regionPS[4096] = buf[1023];
}

// ---- pass A4: scatter points into region buckets + streaming zero of grid C ----
__launch_bounds__(BLK)
__global__ void k_scatterA(const float* __restrict__ X, int n,
                           const int* __restrict__ blockHist,
                           const int* __restrict__ regionPS,
                           float4* __restrict__ bucket, float4* __restrict__ zeroC) {
    __shared__ int cur[NREG];
    for (int i = threadIdx.x; i < NREG; i += blockDim.x) cur[i] = 0;
    __syncthreads();
    int stride = gridDim.x * blockDim.x;
    for (int i = blockIdx.x * blockDim.x + threadIdx.x; i < n; i += stride) {
        float x = X[3 * i + 0], y = X[3 * i + 1], z = X[3 * i + 2];
        int r = regOf(binf(x), binf(y), binf(z));
        int pos = regionPS[r] + blockHist[blockIdx.x * NREG + r] + atomicAdd(&cur[r], 1);
        bucket[pos] = make_float4(x, y, z, __int_as_float(i));
    }
    for (int i = blockIdx.x * blockDim.x + threadIdx.x; i < CELLS; i += stride)
        zeroC[i] = make_float4(0.f, 0.f, 0.f, 0.f);
}

// ---- pass B: one block/region — LDS int-atomic accumulate, compact, PIdx ----
__launch_bounds__(BLK)
__global__ void k_binB(const float4* __restrict__ bucket, const int* __restrict__ regionPS,
                       float4* __restrict__ A, int* __restrict__ E0,
                       int* __restrict__ PIdx, int* __restrict__ gM0) {
    __shared__ unsigned long long aX[RC3], aY[RC3], aZ[RC3];
    __shared__ unsigned aC[RC3];
    __shared__ int cidx[RC3];
    __shared__ int cnt, cur, sBase;
    int r = blockIdx.x;
    for (int c = threadIdx.x; c < RC3; c += blockDim.x) {
        aX[c] = 0ull; aY[c] = 0ull; aZ[c] = 0ull; aC[c] = 0u;
    }
    if (threadIdx.x == 0) { cnt = 0; cur = 0; }
    __syncthreads();
    int start = regionPS[r], end = regionPS[r + 1];
    for (int i = start + threadIdx.x; i < end; i += blockDim.x) {
        float4 p = bucket[i];
        int lc = lcOf(binf(p.x), binf(p.y), binf(p.z));
        atomicAdd(&aX[lc], (unsigned long long)(long long)rintf(p.x * FPS));
        atomicAdd(&aY[lc], (unsigned long long)(long long)rintf(p.y * FPS));
        atomicAdd(&aZ[lc], (unsigned long long)(long long)rintf(p.z * FPS));
        atomicAdd(&aC[lc], 1u);
    }
    __syncthreads();
    int myc = 0;
    for (int c = threadIdx.x; c < RC3; c += blockDim.x)
        if (aC[c] > 0u) ++myc;
    if (myc) atomicAdd(&cnt, myc);
    __syncthreads();
    if (threadIdx.x == 0 && cnt > 0) sBase = atomicAdd(gM0, cnt);
    __syncthreads();
    int rx = r / (RDIM * RDIM), ry = (r / RDIM) % RDIM, rz = r % RDIM;
    for (int c = threadIdx.x; c < RC3; c += blockDim.x) {
        if (aC[c] > 0u) {
            int idx = sBase + atomicAdd(&cur, 1);
            cidx[c] = idx;
            int bx = rx * RC + c / (RC * RC);
            int by = ry * RC + (c / RC) % RC;
            int bz = rz * RC + c % RC;
            int b = flatb(bx, by, bz);
            E0[idx] = b;
            A[b] = make_float4((float)((double)(long long)aX[c] * FPSI),
                               (float)((double)(long long)aY[c] * FPSI),
                               (float)((double)(long long)aZ[c] * FPSI),
                               (float)aC[c]);
        }
    }
    __syncthreads();
    for (int i = start + threadIdx.x; i < end; i += blockDim.x) {
        float4 p = bucket[i];
        int lc = lcOf(binf(p.x), binf(p.y), binf(p.z));
        PIdx[__float_as_int(p.w)] = cidx[lc];
    }
}

// ---- mask -> bin-sorted list (block scan, 1 atomic/block), clears mask ----
__launch_bounds__(BLK)
__global__ void k_compactM(unsigned* __restrict__ mask, int* __restrict__ listOut,
                           int* __restrict__ pKout) {
    __shared__ int scan[BLK];
    __shared__ int sBase;
    int i = blockIdx.x * blockDim.x + threadIdx.x;
    unsigned w = (i < CLW) ? mask[i] : 0u;
    if (i < CLW && w) mask[i] = 0u;
    int c = __popc(w);
    scan[threadIdx.x] = c;
    __syncthreads();
    for (int d = 1; d < BLK; d <<= 1) {
        int add = (threadIdx.x >= (unsigned)d) ? scan[threadIdx.x - d] : 0;
        __syncthreads();
        scan[threadIdx.x] += add;
        __syncthreads();
    }
    if (threadIdx.x == BLK - 1) {
        int tot = scan[BLK - 1];
        sBase = tot ? atomicAdd(pKout, tot) : 0;
    }
    __syncthreads();
    int base = sBase + scan[threadIdx.x] - c;
    int bb = i * 32;
    while (w) {
        int b = __ffs(w) - 1;
        listOut[base++] = bb + b;
        w &= w - 1;
    }
}

// ---- fused per-step kernel ----
// Blocks [0, BC): conv, 51 items/block, 5 threads/item (one dx-plane each),
//   row-contiguous taps, LDS reduce; finalize+scatter+claim by lanes 0..50.
// Blocks [BC, NF): grid-stride misc (upd / targeted clear).
__launch_bounds__(BLK)
__global__ void k_fused(
    const float4* __restrict__ src, const int* __restrict__ list, const int* __restrict__ pK,
    float4* __restrict__ REo, int* __restrict__ IDXo, float4* __restrict__ eposInit,
    float4* __restrict__ tgt, unsigned* __restrict__ clT,
    int updS, const float* __restrict__ X, int n, const int* __restrict__ PIdx,
    const float4* __restrict__ REp, const int* __restrict__ IDXp,
    const int* __restrict__ pM0, float4* __restrict__ epos,
    unsigned* __restrict__ notConv,
    const int* __restrict__ clearList, const int* __restrict__ pKc,
    float4* __restrict__ clearGrid, int lastStep) {
    __shared__ float4 sh[BLK];
    __shared__ unsigned sFlag;
    if (threadIdx.x == 0) sFlag = 0;
    __syncthreads();
    int K = *pK;
    int BC = (K + IPB - 1) / IPB;
    if (BC > NF - 256) BC = NF - 256;    // always keep misc blocks
    const float t5[5] = {1.f, 2.f, 3.f, 2.f, 1.f};
    bool moved = false;

    if ((int)blockIdx.x < BC) {
        // ---------------- conv blocks ----------------
        for (int ib = blockIdx.x; ib * IPB < K; ib += BC) {
            int li = threadIdx.x / 5;
            int dx = threadIdx.x % 5;
            int item = ib * IPB + li;
            float4 part = make_float4(0.f, 0.f, 0.f, 0.f);
            if (li < IPB && item < K) {
                int b = list[item];
                int bx = b / DIM2, rem = b % DIM2;
                int by = rem / DIM, bz = rem % DIM;
                int ix = bx + dx - 2;
                if ((unsigned)ix < (unsigned)DIM) {
                    float wx = t5[dx];
                    if (by >= 2 && by <= DIM - 3 && bz >= 2 && bz <= DIM - 3) {
                        #pragma unroll
                        for (int dy = 0; dy < 5; ++dy) {
                            float wxy = wx * t5[dy];
                            const float4* row = src + flatb(ix, by + dy - 2, bz - 2);
                            #pragma unroll
                            for (int dz = 0; dz < 5; ++dz) {
                                float w = wxy * t5[dz];
                                float4 e = row[dz];
                                part.x = fmaf(w, e.x, part.x);
                                part.y = fmaf(w, e.y, part.y);
                                part.z = fmaf(w, e.z, part.z);
                                part.w = fmaf(w, e.w, part.w);
                            }
                        }
                    } else {
                        for (int dy = 0; dy < 5; ++dy) {
                            int iy = by + dy - 2;
                            if ((unsigned)iy >= (unsigned)DIM) continue;
                            float wxy = wx * t5[dy];
                            for (int dz = 0; dz < 5; ++dz) {
                                int iz = bz + dz - 2;
                                if ((unsigned)iz >= (unsigned)DIM) continue;
                                float w = wxy * t5[dz];
                                float4 e = src[flatb(ix, iy, iz)];
                                part.x = fmaf(w, e.x, part.x);
                                part.y = fmaf(w, e.y, part.y);
                                part.z = fmaf(w, e.z, part.z);
                                part.w = fmaf(w, e.w, part.w);
                            }
                        }
                    }
                }
            }
            sh[threadIdx.x] = part;
            __syncthreads();
            if (threadIdx.x < IPB) {
                int item2 = ib * IPB + threadIdx.x;
                if (item2 < K) {
                    int base5 = threadIdx.x * 5;
                    float4 a0 = sh[base5 + 0], a1 = sh[base5 + 1], a2 = sh[base5 + 2];
                    float4 a3 = sh[base5 + 3], a4 = sh[base5 + 4];
                    float sx = a0.x + a1.x + a2.x + a3.x + a4.x;
                    float sy = a0.y + a1.y + a2.y + a3.y + a4.y;
                    float sz = a0.z + a1.z + a2.z + a3.z + a4.z;
                    float sc = a0.w + a1.w + a2.w + a3.w + a4.w;
                    int b = list[item2];
                    float W = src[b].w;     // center count (occupied => sc>0)
                    float4 np = make_float4(sx / sc, sy / sc, sz / sc, W);
                    REo[item2] = np;
                    IDXo[b] = item2;
                    if (eposInit) eposInit[item2] = np;
                    if (!lastStep) {
                        int bn = flatb(binf(np.x), binf(np.y), binf(np.z));
                        float* cell = (float*)&tgt[bn];
                        pk_add(cell + 0, W * np.x, W * np.y);
                        pk_add(cell + 2, W * np.z, W);
                        atomicOr(&clT[(unsigned)bn >> 5], 1u << (bn & 31));
                    }
                }
            }
            __syncthreads();    // sh reuse
        }
    } else {
        // ---------------- misc blocks ----------------
        int U = (updS > 0) ? (X ? n : *pM0) : 0;
        int CL = clearList ? *pKc : 0;
        int total = U + CL;
        bool done = false;
        if (updS > 1) {
            for (int t = 1; t < updS; ++t) done |= (notConv[t] == 0u);
        }
        int stride = (NF - BC) * blockDim.x;
        for (int idx = (blockIdx.x - BC) * blockDim.x + threadIdx.x; idx < total;
             idx += stride) {
            if (idx < U) {
                int e = idx;
                if (X) {  // per-point step-1 convergence via PIdx
                    float x = X[3 * e + 0], y = X[3 * e + 1], z = X[3 * e + 2];
                    float4 rr = REp[PIdx[e]];
                    float ex = rr.x - x, ey = rr.y - y, ez = rr.z - z;
                    moved |= (fmaf(ex, ex, fmaf(ey, ey, ez * ez)) > TOL2);
                } else if (!done) {  // per-entry update to step-updS position
                    float4 p = epos[e];
                    int j = IDXp[flatb(binf(p.x), binf(p.y), binf(p.z))];
                    float4 rr = REp[j];
                    float ex = rr.x - p.x, ey = rr.y - p.y, ez = rr.z - p.z;
                    moved |= (fmaf(ex, ex, fmaf(ey, ey, ez * ez)) > TOL2);
                    epos[e] = make_float4(rr.x, rr.y, rr.z, p.w);
                }
            } else {
                clearGrid[clearList[idx - U]] = make_float4(0.f, 0.f, 0.f, 0.f);
            }
        }
    }
    if (moved) sFlag = 1;
    __syncthreads();
    if (threadIdx.x == 0 && updS > 0 && sFlag) notConv[updS] = 1u;
}

// ---- finalize: per-entry final position table fpos[e] ----
__launch_bounds__(BLK)
__global__ void k_fin(const float4* __restrict__ REa, const int* __restrict__ IDXa,
                      const float4* __restrict__ epos, const int* __restrict__ pM0,
                      const unsigned* __restrict__ notConv, float4* __restrict__ fpos) {
    int M0 = *pM0;
    bool done = false;
    for (int t = 1; t <= 4; ++t) done |= (notConv[t] == 0u);
    for (int e = blockIdx.x * blockDim.x + threadIdx.x; e < M0;
         e += gridDim.x * blockDim.x) {
        float4 p = epos[e];
        if (!done) {
            float4 rr = REa[IDXa[flatb(binf(p.x), binf(p.y), binf(p.z))]];
            p.x = rr.x; p.y = rr.y; p.z = rr.z;
        }
        fpos[e] = p;
    }
}

// ---- per-point output: single gather through fpos via PIdx ----
__global__ void k_map(const int* __restrict__ PIdx, int n, const float4* __restrict__ fpos,
                      float* __restrict__ out) {
    int i = blockIdx.x * blockDim.x + threadIdx.x;
    if (i >= n) return;
    float4 p = fpos[PIdx[i]];
    out[3 * i + 0] = p.x;
    out[3 * i + 1] = p.y;
    out[3 * i + 2] = p.z;
}

extern "C" void kernel_launch(void* const* d_in, const int* in_sizes, int n_in,
                              void* d_out, int out_size, void* d_ws, size_t ws_size,
                              hipStream_t stream) {
    const float* X = (const float*)d_in[0];
    int n = in_sizes[0] / 3;

    char* ws = (char*)d_ws;
    int*      cnt     = (int*)ws;        // cnt[1..5] list sizes
    unsigned* notConv = (unsigned*)(ws + 32);
    size_t mB = (size_t)CLW * 4;
    size_t gB = (size_t)CELLS * 16;
    unsigned* m0 = (unsigned*)(ws + 256);
    unsigned* m1 = (unsigned*)(ws + 256 + mB);
    float4* A = (float4*)(ws + 256 + 2 * mB);
    float4* B = (float4*)((char*)A + gB);
    float4* C = (float4*)((char*)B + gB);
    int* IDXa = (int*)((char*)C + gB);
    int* IDXb = IDXa + CELLS;
    float4* REa  = (float4*)(IDXb + CELLS);
    float4* REb  = REa + n;
    float4* epos = REb + n;
    int* E0   = (int*)(epos + n);
    int* La   = E0 + n;
    int* Lb   = La + n;
    int* Lc   = Lb + n;
    int* Ld   = Lc + n;
    int* PIdx = Ld + n;
    float4* bucket = (float4*)(PIdx + n);
    int* blockHist = (int*)(bucket + n);
    int* regionPS  = blockHist + NB_A * NREG;

    hipMemsetAsync(ws, 0, 256 + 2 * mB + gB, stream);  // meta+masks+A

    const int NCM = (CLW + BLK - 1) / BLK;   // compactM blocks

    k_histA<<<NB_A, BLK, 0, stream>>>(X, n, blockHist, B);
    k_colscan<<<NREG / BLK, BLK, 0, stream>>>(blockHist, regionPS);
    k_regprefix<<<1, 1024, 0, stream>>>(regionPS);
    k_scatterA<<<NB_A, BLK, 0, stream>>>(X, n, blockHist, regionPS, bucket, C);
    k_binB<<<NREG, BLK, 0, stream>>>(bucket, regionPS, A, E0, PIdx, &cnt[1]);

    // F1: conv A/E0 -> REa/IDXa (+epos init); scatter->B claim m0
    k_fused<<<NF, BLK, 0, stream>>>(A, E0, &cnt[1], REa, IDXa, epos,
                                    B, m0,
                                    0, nullptr, n, nullptr, nullptr, nullptr, nullptr,
                                    nullptr, notConv, nullptr, nullptr, nullptr, 0);
    // sorted list for step 2; clears m0 (free for F3)
    k_compactM<<<NCM, BLK, 0, stream>>>(m0, La, &cnt[2]);
    // F2: conv B/La -> REb/IDXb; scatter->C claim m1; upd1 via PIdx (REa); clear A via E0
    k_fused<<<NF, BLK, 0, stream>>>(B, La, &cnt[2], REb, IDXb, nullptr,
                                    C, m1,
                                    1, X, n, PIdx, REa, IDXa, &cnt[1], nullptr,
                                    notConv, E0, &cnt[1], A, 0);
    k_compactM<<<NCM, BLK, 0, stream>>>(m1, Lb, &cnt[3]);
    // F3: conv C/Lb -> REa/IDXa; scatter->A claim m0; upd2 (REb/IDXb); clear B via La
    k_fused<<<NF, BLK, 0, stream>>>(C, Lb, &cnt[3], REa, IDXa, nullptr,
                                    A, m0,
                                    2, nullptr, n, nullptr, REb, IDXb, &cnt[1], epos,
                                    notConv, La, &cnt[2], B, 0);
    k_compactM<<<NCM, BLK, 0, stream>>>(m0, Lc, &cnt[4]);
    // F4: conv A/Lc -> REb/IDXb; scatter->B claim m1; upd3 (REa/IDXa)
    k_fused<<<NF, BLK, 0, stream>>>(A, Lc, &cnt[4], REb, IDXb, nullptr,
                                    B, m1,
                                    3, nullptr, n, nullptr, REa, IDXa, &cnt[1], epos,
                                    notConv, nullptr, nullptr, nullptr, 0);
    k_compactM<<<NCM, BLK, 0, stream>>>(m1, Ld, &cnt[5]);
    // F5: conv B/Ld -> REa/IDXa (conv only); upd4 (REb/IDXb)
    k_fused<<<NF, BLK, 0, stream>>>(B, Ld, &cnt[5], REa, IDXa, nullptr,
                                    nullptr, nullptr,
                                    4, nullptr, n, nullptr, REb, IDXb, &cnt[1], epos,
                                    notConv, nullptr, nullptr, nullptr, 1);

    k_fin<<<256, BLK, 0, stream>>>(REa, IDXa, epos, &cnt[1], notConv, REb);
    k_map<<<(n + BLK - 1) / BLK, BLK, 0, stream>>>(PIdx, n, REb, (float*)d_out);
}